// Round 1
// baseline (211746.411 us; speedup 1.0000x reference)
//
#include <hip/hip_runtime.h>
#include <cstddef>

#define B_   32
#define TE_  512
#define TD_  512
#define NM_  80
#define PRE_ 256
#define EH_  512
#define AH_  1024
#define AD_  128

__device__ __forceinline__ float sigf(float x) { return 1.0f / (1.0f + expf(-x)); }

// ---------------- prologue: weight packing ----------------
// WTA4 layout: [k4][rp][4] where rp = j*4+g (g: 0=i,1=f,2=g,3=o), k = [wih(768) ; whh(1024)]
// WTD4 layout: same, k = [wih(1536) ; whh(1024)]
__global__ __launch_bounds__(256) void k_pack_big(
    const float* __restrict__ a_wih, const float* __restrict__ a_whh,
    const float* __restrict__ d_wih, const float* __restrict__ d_whh,
    float* __restrict__ wta4, float* __restrict__ wtd4)
{
  int gid = blockIdx.x * 256 + threadIdx.x;
  const int NA = 448 * 4096;   // 1792/4 * 4096
  const int ND = 640 * 4096;   // 2560/4 * 4096
  if (gid < NA) {
    int k4 = gid >> 12, rp = gid & 4095;
    int j = rp >> 2, g = rp & 3, row = g * 1024 + j;
    int k = k4 * 4;
    float4 v;
    if (k < 768) v = *(const float4*)(a_wih + (size_t)row * 768 + k);
    else         v = *(const float4*)(a_whh + (size_t)row * 1024 + (k - 768));
    *(float4*)(wta4 + (size_t)gid * 4) = v;
  } else if (gid < NA + ND) {
    int g2 = gid - NA;
    int k4 = g2 >> 12, rp = g2 & 4095;
    int j = rp >> 2, g = rp & 3, row = g * 1024 + j;
    int k = k4 * 4;
    float4 v;
    if (k < 1536) v = *(const float4*)(d_wih + (size_t)row * 1536 + k);
    else          v = *(const float4*)(d_whh + (size_t)row * 1024 + (k - 1536));
    *(float4*)(wtd4 + (size_t)g2 * 4) = v;
  }
}

// small transposes + fused conv*L tensor + bias sums
__global__ __launch_bounds__(256) void k_pack_small(
    const float* __restrict__ w1, const float* __restrict__ w2,
    const float* __restrict__ mw, const float* __restrict__ qw,
    const float* __restrict__ pw, const float* __restrict__ abih,
    const float* __restrict__ abhh, const float* __restrict__ dbih,
    const float* __restrict__ dbhh, const float* __restrict__ lw,
    const float* __restrict__ cw,
    float* __restrict__ w1t, float* __restrict__ w2t, float* __restrict__ mt,
    float* __restrict__ qt, float* __restrict__ pjt,
    float* __restrict__ ba, float* __restrict__ bd, float* __restrict__ lc)
{
  int gid = blockIdx.x * 256 + threadIdx.x;
  if (gid < 20480) { int k = gid / 256, j = gid % 256; w1t[gid] = w1[j * 80 + k]; return; }
  gid -= 20480;
  if (gid < 65536) { int k = gid / 256, j = gid % 256; w2t[gid] = w2[j * 256 + k]; return; }
  gid -= 65536;
  if (gid < 65536) { int e = gid / 128, d = gid % 128; mt[gid] = mw[d * 512 + e]; return; }
  gid -= 65536;
  if (gid < 131072) { int j = gid / 128, d = gid % 128; qt[gid] = qw[d * 1024 + j]; return; }
  gid -= 131072;
  if (gid < 122880) { int k = gid / 80, m = gid % 80; pjt[gid] = pw[m * 1536 + k]; return; }
  gid -= 122880;
  if (gid < 4096) { int j = gid >> 2, g = gid & 3, row = g * 1024 + j; ba[gid] = abih[row] + abhh[row]; return; }
  gid -= 4096;
  if (gid < 4096) { int j = gid >> 2, g = gid & 3, row = g * 1024 + j; bd[gid] = dbih[row] + dbhh[row]; return; }
  gid -= 4096;
  if (gid < 7936) {
    int c = gid / (31 * 128), rem = gid % (31 * 128);
    int kk = rem / 128, d = rem % 128;
    float s = 0.f;
    for (int f = 0; f < 32; ++f) s += lw[d * 32 + f] * cw[(f * 2 + c) * 31 + kk];
    lc[gid] = s;
  }
}

// ---------------- prologue: prenet over all (b,t) ----------------
// PN layout: [t][k<256][b]
__global__ __launch_bounds__(256) void k_prenet(
    const float* __restrict__ targets, const float* __restrict__ w1t,
    const float* __restrict__ b1, const float* __restrict__ w2t,
    const float* __restrict__ b2, float* __restrict__ pn)
{
  int t = blockIdx.x, tid = threadIdx.x;
  __shared__ float X[32][80];
  __shared__ float h1[256][33];
  for (int i = tid; i < 2560; i += 256) {
    int b = i / 80, m = i % 80;
    X[b][m] = (t == 0) ? 0.f : targets[((size_t)b * TD_ + (t - 1)) * NM_ + m];
  }
  __syncthreads();
  int j = tid;
  float bj = b1[j];
  for (int bt = 0; bt < 4; ++bt) {
    float acc[8];
#pragma unroll
    for (int i = 0; i < 8; ++i) acc[i] = bj;
    for (int k = 0; k < 80; ++k) {
      float w = w1t[k * 256 + j];
#pragma unroll
      for (int i = 0; i < 8; ++i) acc[i] += w * X[bt * 8 + i][k];
    }
#pragma unroll
    for (int i = 0; i < 8; ++i) h1[j][bt * 8 + i] = fmaxf(acc[i], 0.f);
  }
  __syncthreads();
  float cj = b2[j];
  float* out = pn + (size_t)t * PRE_ * B_;
  for (int bt = 0; bt < 4; ++bt) {
    float acc[8];
#pragma unroll
    for (int i = 0; i < 8; ++i) acc[i] = cj;
    for (int k = 0; k < 256; ++k) {
      float w = w2t[k * 256 + j];
#pragma unroll
      for (int i = 0; i < 8; ++i) acc[i] += w * h1[k][bt * 8 + i];
    }
#pragma unroll
    for (int i = 0; i < 8; ++i) out[j * 32 + bt * 8 + i] = fmaxf(acc[i], 0.f);
  }
}

// ---------------- prologue: processed_enc = enc @ M_w^T ----------------
// PENC layout: [t][d<128][b]
__global__ __launch_bounds__(256) void k_penc(
    const float* __restrict__ enc, const float* __restrict__ mt,
    float* __restrict__ penc)
{
  int t = blockIdx.x, tid = threadIdx.x;
  __shared__ float encL[32][256];
  __shared__ float red[128][8][2];
  int d = tid & 127, s = tid >> 7;
  float acc[4][8];
#pragma unroll
  for (int bt = 0; bt < 4; ++bt)
#pragma unroll
    for (int i = 0; i < 8; ++i) acc[bt][i] = 0.f;
  for (int eh = 0; eh < 2; ++eh) {
    for (int i = tid; i < 8192; i += 256) {
      int b = i >> 8, e = i & 255;
      encL[b][e] = enc[((size_t)b * TE_ + t) * EH_ + eh * 256 + e];
    }
    __syncthreads();
    for (int bt = 0; bt < 4; ++bt) {
      for (int el = s * 128; el < s * 128 + 128; ++el) {
        float w = mt[(eh * 256 + el) * 128 + d];
#pragma unroll
        for (int i = 0; i < 8; ++i) acc[bt][i] += w * encL[bt * 8 + i][el];
      }
    }
    __syncthreads();
  }
  for (int bt = 0; bt < 4; ++bt) {
#pragma unroll
    for (int i = 0; i < 8; ++i) red[d][i][s] = acc[bt][i];
    __syncthreads();
    if (s == 0) {
#pragma unroll
      for (int i = 0; i < 8; ++i)
        penc[((size_t)t * AD_ + d) * 32 + bt * 8 + i] = red[d][i][0] + red[d][i][1];
    }
    __syncthreads();
  }
}

// ---------------- step kernel A: attention LSTM (+ fused mel-out of step t-1) ----------------
__global__ __launch_bounds__(512) void k_lstm_a(
    const float* __restrict__ wta4, const float* __restrict__ pn_t,
    const float* __restrict__ ctx, const float* __restrict__ ah_r,
    float* __restrict__ ah_w, float* __restrict__ ac,
    const float* __restrict__ ba,
    const float* __restrict__ dh_prev, const float* __restrict__ pjt,
    const float* __restrict__ projb, float* __restrict__ mel, int t)
{
  int tid = threadIdx.x;
  if (blockIdx.x < 256) {
    __shared__ float red[16][33][8];
    __shared__ float gbuf[16][33];
    int rl = tid & 15, bq = (tid >> 4) & 3, ks = tid >> 6;
    int rp0 = blockIdx.x * 16, b0 = bq * 8;
    float4 a0 = {0, 0, 0, 0}, a1 = {0, 0, 0, 0};
    int k40 = ks * 56;
    for (int k4 = k40; k4 < k40 + 56; ++k4) {
      float4 w4 = *(const float4*)(wta4 + ((size_t)k4 * 4096 + rp0 + rl) * 4);
      const float* xrow;
      if (k4 < 64)       xrow = pn_t + k4 * 4 * 32;
      else if (k4 < 192) xrow = ctx + (k4 * 4 - 256) * 32;
      else               xrow = ah_r + (k4 * 4 - 768) * 32;
#pragma unroll
      for (int e = 0; e < 4; ++e) {
        float we = (e == 0) ? w4.x : (e == 1) ? w4.y : (e == 2) ? w4.z : w4.w;
        float4 xa = *(const float4*)(xrow + e * 32 + b0);
        float4 xb = *(const float4*)(xrow + e * 32 + b0 + 4);
        a0.x += we * xa.x; a0.y += we * xa.y; a0.z += we * xa.z; a0.w += we * xa.w;
        a1.x += we * xb.x; a1.y += we * xb.y; a1.z += we * xb.z; a1.w += we * xb.w;
      }
    }
    red[rl][b0 + 0][ks] = a0.x; red[rl][b0 + 1][ks] = a0.y;
    red[rl][b0 + 2][ks] = a0.z; red[rl][b0 + 3][ks] = a0.w;
    red[rl][b0 + 4][ks] = a1.x; red[rl][b0 + 5][ks] = a1.y;
    red[rl][b0 + 6][ks] = a1.z; red[rl][b0 + 7][ks] = a1.w;
    __syncthreads();
    {
      int rl2 = tid & 15, b2 = tid >> 4;
      float s = 0.f;
#pragma unroll
      for (int k = 0; k < 8; ++k) s += red[rl2][b2][k];
      gbuf[rl2][b2] = s;
    }
    __syncthreads();
    if (tid < 128) {
      int jl = tid & 3, bb = tid >> 2;
      float gi = gbuf[jl * 4 + 0][bb] + ba[rp0 + jl * 4 + 0];
      float gf = gbuf[jl * 4 + 1][bb] + ba[rp0 + jl * 4 + 1];
      float gg = gbuf[jl * 4 + 2][bb] + ba[rp0 + jl * 4 + 2];
      float go = gbuf[jl * 4 + 3][bb] + ba[rp0 + jl * 4 + 3];
      int j = (rp0 >> 2) + jl;
      float c0 = ac[j * 32 + bb];
      float c2 = sigf(gf) * c0 + sigf(gi) * tanhf(gg);
      float h2 = sigf(go) * tanhf(c2);
      ac[j * 32 + bb] = c2;
      ah_w[j * 32 + bb] = h2;
    }
  } else {
    // fused mel projection for step t-1 (dh_{t-1}, ctx_{t-1} both still live)
    if (t == 0) return;
    int b = blockIdx.x - 256;
    __shared__ float xo[1536];
    __shared__ float ro[80][7];
    for (int i = tid; i < 1536; i += 512)
      xo[i] = (i < 1024) ? dh_prev[i * 32 + b] : ctx[(i - 1024) * 32 + b];
    __syncthreads();
    if (tid < 480) {
      int m = tid % 80, k2 = tid / 80;
      float acc2 = 0.f;
      for (int k = k2 * 256; k < k2 * 256 + 256; ++k) acc2 += pjt[k * 80 + m] * xo[k];
      ro[m][k2] = acc2;
    }
    __syncthreads();
    if (tid < 80) {
      float s = projb[tid];
#pragma unroll
      for (int k = 0; k < 6; ++k) s += ro[tid][k];
      mel[((size_t)b * TD_ + (t - 1)) * NM_ + tid] = s;
    }
  }
}

// ---------------- step kernel Q: q = ah_t @ Q_w^T ----------------
__global__ __launch_bounds__(256) void k_q(
    const float* __restrict__ ah, const float* __restrict__ qt,
    float* __restrict__ q)
{
  int b = blockIdx.x, tid = threadIdx.x;
  __shared__ float ahL[1024];
  __shared__ float qred[2][128];
  for (int j2 = tid; j2 < 1024; j2 += 256) ahL[j2] = ah[j2 * 32 + b];
  __syncthreads();
  int d = tid & 127, s = tid >> 7;
  float acc = 0.f;
  for (int j2 = s * 512; j2 < s * 512 + 512; ++j2) acc += qt[j2 * 128 + d] * ahL[j2];
  qred[s][d] = acc;
  __syncthreads();
  if (tid < 128) q[tid * 32 + b] = qred[0][tid] + qred[1][tid];
}

// ---------------- step kernel B: energies (location conv fused via LC) ----------------
__global__ __launch_bounds__(512) void k_energies(
    const float* __restrict__ aw, const float* __restrict__ aws,
    const float* __restrict__ lc, const float* __restrict__ q,
    const float* __restrict__ penc, const float* __restrict__ ww,
    float* __restrict__ en)
{
  int t0 = blockIdx.x * 2, tid = threadIdx.x;
  __shared__ float win[2][32][32];
  __shared__ float lcs[7936];
  __shared__ float qs[4096];
  __shared__ float wws[128];
  __shared__ float er[2][8][32];
  for (int i = tid; i < 2048; i += 512) {
    int c = i >> 10, r = (i >> 5) & 31, bb = i & 31;
    int tg = t0 - 15 + r;
    float v = 0.f;
    if (tg >= 0 && tg < 512) v = (c == 0 ? aw : aws)[tg * 32 + bb];
    win[c][r][bb] = v;
  }
  for (int i = tid; i < 7936; i += 512) lcs[i] = lc[i];
  for (int i = tid; i < 4096; i += 512) qs[i] = q[i];
  if (tid < 128) wws[tid] = ww[tid];
  __syncthreads();
  int b = tid & 31, dh8 = (tid >> 5) & 7, th = tid >> 8;
  int tp = t0 + th, d0 = dh8 * 16;
  float pa[16];
#pragma unroll
  for (int i = 0; i < 16; ++i) pa[i] = 0.f;
  for (int c = 0; c < 2; ++c) {
    for (int kk = 0; kk < 31; ++kk) {
      float sv = win[c][th + kk][b];
      const float* lrow = lcs + (c * 31 + kk) * 128 + d0;
#pragma unroll
      for (int i = 0; i < 16; ++i) pa[i] += lrow[i] * sv;
    }
  }
  float ep = 0.f;
  const float* prow = penc + ((size_t)tp * 128 + d0) * 32 + b;
#pragma unroll
  for (int i = 0; i < 16; ++i) {
    float v = qs[(d0 + i) * 32 + b] + prow[i * 32] + pa[i];
    ep += wws[d0 + i] * tanhf(v);
  }
  er[th][dh8][b] = ep;
  __syncthreads();
  if (tid < 64) {
    int th2 = tid >> 5, bb = tid & 31;
    float s = 0.f;
#pragma unroll
    for (int k = 0; k < 8; ++k) s += er[th2][k][bb];
    en[(size_t)(t0 + th2) * 32 + bb] = s;
  }
}

// ---------------- step kernel C: softmax + ctx + aw/aws/alignments ----------------
__global__ __launch_bounds__(256) void k_ctx(
    const float* __restrict__ en, const float* __restrict__ enc,
    float* __restrict__ ctx, float* __restrict__ aw, float* __restrict__ aws,
    float* __restrict__ align, int t)
{
  int bid = blockIdx.x;
  int b = bid >> 3, et = bid & 7;
  int tid = threadIdx.x;
  __shared__ float awL[512];
  __shared__ float r1[256];
  __shared__ float cr[4][64];
  float e0 = en[tid * 32 + b], e1 = en[(tid + 256) * 32 + b];
  r1[tid] = fmaxf(e0, e1);
  __syncthreads();
  for (int off = 128; off > 0; off >>= 1) {
    if (tid < off) r1[tid] = fmaxf(r1[tid], r1[tid + off]);
    __syncthreads();
  }
  float mx = r1[0];
  __syncthreads();
  float x0 = expf(e0 - mx), x1 = expf(e1 - mx);
  r1[tid] = x0 + x1;
  __syncthreads();
  for (int off = 128; off > 0; off >>= 1) {
    if (tid < off) r1[tid] += r1[tid + off];
    __syncthreads();
  }
  float inv = 1.0f / r1[0];
  awL[tid] = x0 * inv;
  awL[tid + 256] = x1 * inv;
  __syncthreads();
  int el = tid & 63, ts = tid >> 6;
  const float* ebase = enc + (size_t)b * TE_ * EH_ + et * 64 + el;
  float acc = 0.f;
  for (int t2 = ts * 128; t2 < ts * 128 + 128; ++t2)
    acc += awL[t2] * ebase[(size_t)t2 * EH_];
  cr[ts][el] = acc;
  __syncthreads();
  if (tid < 64) {
    float s = cr[0][tid] + cr[1][tid] + cr[2][tid] + cr[3][tid];
    ctx[(et * 64 + tid) * 32 + b] = s;
  }
  if (et == 0) {
    for (int t2 = tid; t2 < 512; t2 += 256) {
      float a = awL[t2];
      aw[t2 * 32 + b] = a;
      aws[t2 * 32 + b] += a;
      align[((size_t)b * TD_ + t) * TE_ + t2] = a;
    }
  }
}

// ---------------- step kernel D: decoder LSTM ----------------
__global__ __launch_bounds__(512) void k_lstm_d(
    const float* __restrict__ wtd4, const float* __restrict__ ah_cur,
    const float* __restrict__ ctx, const float* __restrict__ dh_r,
    float* __restrict__ dh_w, float* __restrict__ dc,
    const float* __restrict__ bd)
{
  int tid = threadIdx.x;
  __shared__ float red[16][33][8];
  __shared__ float gbuf[16][33];
  int rl = tid & 15, bq = (tid >> 4) & 3, ks = tid >> 6;
  int rp0 = blockIdx.x * 16, b0 = bq * 8;
  float4 a0 = {0, 0, 0, 0}, a1 = {0, 0, 0, 0};
  int k40 = ks * 80;
  for (int k4 = k40; k4 < k40 + 80; ++k4) {
    float4 w4 = *(const float4*)(wtd4 + ((size_t)k4 * 4096 + rp0 + rl) * 4);
    const float* xrow;
    if (k4 < 256)      xrow = ah_cur + k4 * 4 * 32;
    else if (k4 < 384) xrow = ctx + (k4 * 4 - 1024) * 32;
    else               xrow = dh_r + (k4 * 4 - 1536) * 32;
#pragma unroll
    for (int e = 0; e < 4; ++e) {
      float we = (e == 0) ? w4.x : (e == 1) ? w4.y : (e == 2) ? w4.z : w4.w;
      float4 xa = *(const float4*)(xrow + e * 32 + b0);
      float4 xb = *(const float4*)(xrow + e * 32 + b0 + 4);
      a0.x += we * xa.x; a0.y += we * xa.y; a0.z += we * xa.z; a0.w += we * xa.w;
      a1.x += we * xb.x; a1.y += we * xb.y; a1.z += we * xb.z; a1.w += we * xb.w;
    }
  }
  red[rl][b0 + 0][ks] = a0.x; red[rl][b0 + 1][ks] = a0.y;
  red[rl][b0 + 2][ks] = a0.z; red[rl][b0 + 3][ks] = a0.w;
  red[rl][b0 + 4][ks] = a1.x; red[rl][b0 + 5][ks] = a1.y;
  red[rl][b0 + 6][ks] = a1.z; red[rl][b0 + 7][ks] = a1.w;
  __syncthreads();
  {
    int rl2 = tid & 15, b2 = tid >> 4;
    float s = 0.f;
#pragma unroll
    for (int k = 0; k < 8; ++k) s += red[rl2][b2][k];
    gbuf[rl2][b2] = s;
  }
  __syncthreads();
  if (tid < 128) {
    int jl = tid & 3, bb = tid >> 2;
    float gi = gbuf[jl * 4 + 0][bb] + bd[rp0 + jl * 4 + 0];
    float gf = gbuf[jl * 4 + 1][bb] + bd[rp0 + jl * 4 + 1];
    float gg = gbuf[jl * 4 + 2][bb] + bd[rp0 + jl * 4 + 2];
    float go = gbuf[jl * 4 + 3][bb] + bd[rp0 + jl * 4 + 3];
    int j = (rp0 >> 2) + jl;
    float c0 = dc[j * 32 + bb];
    float c2 = sigf(gf) * c0 + sigf(gi) * tanhf(gg);
    float h2 = sigf(go) * tanhf(c2);
    dc[j * 32 + bb] = c2;
    dh_w[j * 32 + bb] = h2;
  }
}

// ---------------- final mel row (t = 511) ----------------
__global__ __launch_bounds__(512) void k_out(
    const float* __restrict__ dh, const float* __restrict__ ctx,
    const float* __restrict__ pjt, const float* __restrict__ projb,
    float* __restrict__ mel, int t)
{
  int b = blockIdx.x, tid = threadIdx.x;
  __shared__ float xo[1536];
  __shared__ float ro[80][7];
  for (int i = tid; i < 1536; i += 512)
    xo[i] = (i < 1024) ? dh[i * 32 + b] : ctx[(i - 1024) * 32 + b];
  __syncthreads();
  if (tid < 480) {
    int m = tid % 80, k2 = tid / 80;
    float acc2 = 0.f;
    for (int k = k2 * 256; k < k2 * 256 + 256; ++k) acc2 += pjt[k * 80 + m] * xo[k];
    ro[m][k2] = acc2;
  }
  __syncthreads();
  if (tid < 80) {
    float s = projb[tid];
#pragma unroll
    for (int k = 0; k < 6; ++k) s += ro[tid][k];
    mel[((size_t)b * TD_ + t) * NM_ + tid] = s;
  }
}

extern "C" void kernel_launch(void* const* d_in, const int* in_sizes, int n_in,
                              void* d_out, int out_size, void* d_ws, size_t ws_size,
                              hipStream_t stream)
{
  const float* enc     = (const float*)d_in[0];
  const float* targets = (const float*)d_in[1];
  const float* pw1  = (const float*)d_in[2];
  const float* pb1  = (const float*)d_in[3];
  const float* pw2  = (const float*)d_in[4];
  const float* pb2  = (const float*)d_in[5];
  const float* mw   = (const float*)d_in[6];
  const float* qw   = (const float*)d_in[7];
  const float* www  = (const float*)d_in[8];
  const float* lw   = (const float*)d_in[9];
  const float* cw   = (const float*)d_in[10];
  const float* awih = (const float*)d_in[11];
  const float* awhh = (const float*)d_in[12];
  const float* abih = (const float*)d_in[13];
  const float* abhh = (const float*)d_in[14];
  const float* dwih = (const float*)d_in[15];
  const float* dwhh = (const float*)d_in[16];
  const float* dbih = (const float*)d_in[17];
  const float* dbhh = (const float*)d_in[18];
  const float* pjw  = (const float*)d_in[19];
  const float* pjb  = (const float*)d_in[20];

  float* ws = (float*)d_ws;
  float* WTA4 = ws;                       // 7,340,032
  float* WTD4 = WTA4 + 7340032;           // 10,485,760
  float* PN   = WTD4 + 10485760;          // 4,194,304
  float* PENC = PN + 4194304;             // 2,097,152
  float* W1T  = PENC + 2097152;           // 20,480
  float* W2T  = W1T + 20480;              // 65,536
  float* MT   = W2T + 65536;              // 65,536
  float* QT   = MT + 65536;               // 131,072
  float* PJT  = QT + 131072;              // 122,880
  float* LC   = PJT + 122880;             // 7,936
  float* BA   = LC + 7936;                // 4,096
  float* BD   = BA + 4096;                // 4,096
  float* AHb  = BD + 4096;                // 65,536 (2 parities)
  float* ACb  = AHb + 65536;              // 32,768
  float* DHb  = ACb + 32768;              // 65,536 (2 parities)
  float* DCb  = DHb + 65536;              // 32,768
  float* CTXb = DCb + 32768;              // 16,384
  float* AWb  = CTXb + 16384;             // 16,384
  float* AWSb = AWb + 16384;              // 16,384
  float* ENb  = AWSb + 16384;             // 16,384
  float* Qb   = ENb + 16384;              // 4,096

  // zero recurrent state (ws is poisoned before every launch)
  hipMemsetAsync(AHb, 0,
                 (size_t)(65536 + 32768 + 65536 + 32768 + 16384 + 16384 + 16384) * sizeof(float),
                 stream);

  float* mel = (float*)d_out;
  float* align = mel + (size_t)B_ * TD_ * NM_;

  k_pack_big<<<17408, 256, 0, stream>>>(awih, awhh, dwih, dwhh, WTA4, WTD4);
  k_pack_small<<<1647, 256, 0, stream>>>(pw1, pw2, mw, qw, pjw, abih, abhh, dbih, dbhh,
                                         lw, cw, W1T, W2T, MT, QT, PJT, BA, BD, LC);
  k_prenet<<<512, 256, 0, stream>>>(targets, W1T, pb1, W2T, pb2, PN);
  k_penc<<<512, 256, 0, stream>>>(enc, MT, PENC);

  for (int t = 0; t < TD_; ++t) {
    int pr = t & 1, pw = 1 - pr;
    k_lstm_a<<<288, 512, 0, stream>>>(WTA4, PN + (size_t)t * PRE_ * B_, CTXb,
                                      AHb + pr * 32768, AHb + pw * 32768, ACb, BA,
                                      DHb + pr * 32768, PJT, pjb, mel, t);
    k_q<<<32, 256, 0, stream>>>(AHb + pw * 32768, QT, Qb);
    k_energies<<<256, 512, 0, stream>>>(AWb, AWSb, LC, Qb, PENC, www, ENb);
    k_ctx<<<256, 256, 0, stream>>>(ENb, enc, CTXb, AWb, AWSb, align, t);
    k_lstm_d<<<256, 512, 0, stream>>>(WTD4, AHb + pw * 32768, CTXb,
                                      DHb + pr * 32768, DHb + pw * 32768, DCb, BD);
  }
  k_out<<<32, 512, 0, stream>>>(DHb + 0, CTXb, PJT, pjb, mel, 511);
}